// Round 3
// baseline (1294.579 us; speedup 1.0000x reference)
//
#include <hip/hip_runtime.h>

typedef unsigned short u16;
typedef __bf16 bf16x8 __attribute__((ext_vector_type(8)));
typedef float f32x4 __attribute__((ext_vector_type(4)));

#define N_NODES 50000
#define N_EDGES 300000
#define NP      12800000   // N_NODES*256
#define NE8     400000     // N_NODES*8

// ---------------- workspace layout (bytes), total ~122.9 MB ----------------
#define WP_OFF    0L            // packed weights bf16: 4 mats * 65536 * 2B = 524288
#define ATTN_OFF  524288L       // 4*512 f32 = 8192
#define ALPHA_OFF 532480L       // 2 f32 (+pad to 64)
#define P_OFF     532544L       // 4*NP bf16 = 102400000
#define EL_OFF    102932544L    // 4*NE8 f32 = 6400000
#define ER_OFF    109332544L    // 6400000
#define CNT_OFF   115732544L    // 4*N int = 800000
#define CUR_OFF   116532544L    // 800000
#define ROW_OFF   117332544L    // 4*(N+1) int = 800016
#define BS_OFF    118132560L    // 4*196 int = 3136
#define COL_OFF   118135696L    // 4*E int = 4800000  -> end 122935696

__device__ __forceinline__ float bf2f(u16 u){
  union { unsigned int i; float f; } v; v.i = ((unsigned int)u) << 16; return v.f;
}
__device__ __forceinline__ u16 f2bf(float f){
  union { float f; unsigned int i; } v; v.f = f;
  unsigned int x = v.i;
  x += 0x7fffu + ((x >> 16) & 1u);   // round-to-nearest-even
  return (u16)(x >> 16);
}
__device__ __forceinline__ float leaky(float x){ return x >= 0.f ? x : 0.2f * x; }

// ---------------- small setup: attn vectors, rel_out, alphas (all fp32) ----------------
__global__ void small_k(const float* __restrict__ rel_feats, const float* __restrict__ Wr,
                        const float* __restrict__ Wupd, const float* __restrict__ bupd,
                        const float* __restrict__ resw,
                        float* __restrict__ attn, float* __restrict__ alpha,
                        float* __restrict__ out_tail){
  int r = blockIdx.x, t = threadIdx.x;
  for (int j = t; j < 512; j += 256){
    float s = 0.f;
    for (int d = 0; d < 64; ++d)
      s += rel_feats[r*64 + d] * Wr[(r*64 + d)*512 + j];
    attn[r*512 + j] = s;
  }
  {
    float s = 0.f;
    for (int d = 0; d < 64; ++d)
      s += rel_feats[r*64 + d] * Wupd[(r*64 + d)*256 + t];
    out_tail[r*256 + t] = s + bupd[r*256 + t];
  }
  if (r == 0 && t < 2) alpha[t] = 1.f / (1.f + __expf(-resw[t]));
}

// ---------------- prepack fp32 weights to bf16 MFMA-B fragment layout ----------------
// Wp[m][kt][n][kk] = bf16(W[m][kt*32+kk][n]);  m: 0,1 = W_node[0..1], 2,3 = Wres[0..1]
__global__ void prepack_k(const float* __restrict__ Wn, const float* __restrict__ Wres,
                          u16* __restrict__ Wp){
  int tid = blockIdx.x*256 + threadIdx.x;          // < 262144
  int m = tid >> 16, rem = tid & 65535;
  int kt = rem >> 13, rem2 = rem & 8191;
  int n = rem2 >> 5, kk = rem2 & 31;
  const float* src = (m < 2) ? (Wn + m*65536) : (Wres + (m - 2)*65536);
  Wp[tid] = f2bf(src[(kt*32 + kk)*256 + n]);
}

// ---------------- GEMM: 256x256 bf16 weight, fp32 A, M=50000 ----------------
// Pout!=null : Pout = bf16(A@W)                     (projection)
// Pout==null : out  = al*conv + (1-al)*(A@W + bias) (residual blend, in-place on out=conv)
__global__ __launch_bounds__(256) void gemm_k(const float* __restrict__ A, const u16* __restrict__ Wp,
                                              const float* __restrict__ bias,
                                              const float* __restrict__ alpha_ws, int tix,
                                              u16* __restrict__ Pout, float* __restrict__ out){
  __shared__ __align__(16) u16 Bt[256*40];   // 32-k slice, padded 32->40 (2-way bank = free)
  const int tid = threadIdx.x;
  const int lane = tid & 63, wave = tid >> 6;
  const int quad = lane >> 4, n0 = lane & 15;
  const int wrow = blockIdx.x*64 + wave*16;
  const int ar = wrow + n0;
  f32x4 acc[16];
#pragma unroll
  for (int i = 0; i < 16; ++i) acc[i] = f32x4{0.f, 0.f, 0.f, 0.f};

  for (int kt = 0; kt < 8; ++kt){
    __syncthreads();
#pragma unroll
    for (int c = 0; c < 4; ++c){
      int ci = tid + c*256;
      int n = ci >> 2, g = ci & 3;
      *(uint4*)(Bt + n*40 + g*8) = *(const uint4*)(Wp + kt*8192 + n*32 + g*8);
    }
    __syncthreads();
    union { bf16x8 v; u16 s[8]; } af;
    if (ar < N_NODES){
      const float* ap = A + (size_t)ar*256 + kt*32 + quad*8;
      f32x4 a0 = *(const f32x4*)ap;
      f32x4 a1 = *(const f32x4*)(ap + 4);
#pragma unroll
      for (int j = 0; j < 4; ++j){ af.s[j] = f2bf(a0[j]); af.s[4+j] = f2bf(a1[j]); }
    } else {
#pragma unroll
      for (int j = 0; j < 8; ++j) af.s[j] = 0;
    }
#pragma unroll
    for (int nt = 0; nt < 16; ++nt){
      bf16x8 bfr = *(const bf16x8*)(Bt + (nt*16 + n0)*40 + quad*8);
      acc[nt] = __builtin_amdgcn_mfma_f32_16x16x32_bf16(af.v, bfr, acc[nt], 0, 0, 0);
    }
  }
  const bool blend = (Pout == nullptr);
  float al = blend ? alpha_ws[tix] : 0.f;
#pragma unroll
  for (int nt = 0; nt < 16; ++nt){
    int col = nt*16 + n0;
    float b = blend ? bias[col] : 0.f;
#pragma unroll
    for (int reg = 0; reg < 4; ++reg){
      int row = wrow + quad*4 + reg;
      if (row < N_NODES){
        if (blend){
          size_t ix = (size_t)row*256 + col;
          out[ix] = al * out[ix] + (1.f - al) * (acc[nt][reg] + b);
        } else {
          Pout[(size_t)row*256 + col] = f2bf(acc[nt][reg]);
        }
      }
    }
  }
}

// ---------------- el / er per relation ----------------
// EL[r][n][k] = dot(P[r^1][n][k*32:], attnL[r][k]);  ER[r][n][k] = dot(P[r][n][k*32:], attnR[r][k])
__global__ void elr_k(const u16* __restrict__ P, const float* __restrict__ attn,
                      float* __restrict__ EL, float* __restrict__ ER){
  int r = blockIdx.y;
  int idx = blockIdx.x*256 + threadIdx.x;
  if (idx >= NE8) return;
  int n = idx >> 3, k = idx & 7;
  const u16* pl = P + (size_t)(r ^ 1)*NP + (size_t)n*256 + k*32;
  const u16* pr = P + (size_t)r*NP       + (size_t)n*256 + k*32;
  const float* aL = attn + r*512 + k*64;
  const float* aR = aL + 32;
  float sl = 0.f, sr = 0.f;
  for (int d = 0; d < 32; ++d){
    sl += bf2f(pl[d]) * aL[d];
    sr += bf2f(pr[d]) * aR[d];
  }
  EL[(size_t)r*NE8 + idx] = sl;
  ER[(size_t)r*NE8 + idx] = sr;
}

// ---------------- CSR build ----------------
__global__ void zero_k(int* __restrict__ p, int n){
  int i = blockIdx.x*256 + threadIdx.x; if (i < n) p[i] = 0;
}
__global__ void hist_k(const int* __restrict__ sr, const int* __restrict__ dr,
                       const int* __restrict__ sc, const int* __restrict__ dc,
                       int* __restrict__ counts){
  int r = blockIdx.y; int e = blockIdx.x*256 + threadIdx.x;
  if (e >= N_EDGES) return;
  const int* dst = (r == 0) ? dr : (r == 1) ? sr : (r == 2) ? dc : sc;
  atomicAdd(&counts[r*N_NODES + dst[e]], 1);
}
__global__ void scan1_k(const int* __restrict__ counts, int* __restrict__ rowptr,
                        int* __restrict__ bsums){
  int r = blockIdx.y; int i = blockIdx.x*256 + threadIdx.x;
  int lane = threadIdx.x & 63, wave = threadIdx.x >> 6;
  int v = (i < N_NODES) ? counts[r*N_NODES + i] : 0;
  int orig = v;
  for (int off = 1; off < 64; off <<= 1){ int t = __shfl_up(v, off); if (lane >= off) v += t; }
  __shared__ int wsum[4];
  if (lane == 63) wsum[wave] = v;
  __syncthreads();
  int add = 0;
  for (int w = 0; w < wave; ++w) add += wsum[w];
  v += add;
  if (i < N_NODES) rowptr[r*(N_NODES+1) + i] = v - orig;   // exclusive within block
  if (threadIdx.x == 255) bsums[r*196 + blockIdx.x] = v;
}
__global__ void scan2_k(int* __restrict__ bsums){   // 1 block; wave r scans its 196 sums
  int lane = threadIdx.x & 63, r = threadIdx.x >> 6;
  int carry = 0;
  for (int c = 0; c < 4; ++c){
    int i = c*64 + lane;
    int v = (i < 196) ? bsums[r*196 + i] : 0;
    int orig = v;
    for (int off = 1; off < 64; off <<= 1){ int t = __shfl_up(v, off); if (lane >= off) v += t; }
    int excl = v - orig + carry;
    if (i < 196) bsums[r*196 + i] = excl;
    carry += __shfl(v, 63);
  }
}
__global__ void scan3_k(const int* __restrict__ bsums, int* __restrict__ rowptr){
  int r = blockIdx.y; int i = blockIdx.x*256 + threadIdx.x;
  if (i < N_NODES) rowptr[r*(N_NODES+1) + i] += bsums[r*196 + blockIdx.x];
  if (i == N_NODES) rowptr[r*(N_NODES+1) + N_NODES] = N_EDGES;
}
__global__ void scatter_k(const int* __restrict__ sr, const int* __restrict__ dr,
                          const int* __restrict__ sc, const int* __restrict__ dc,
                          const int* __restrict__ rowptr, int* __restrict__ cur,
                          int* __restrict__ colsrc){
  int r = blockIdx.y; int e = blockIdx.x*256 + threadIdx.x;
  if (e >= N_EDGES) return;
  const int* dst = (r == 0) ? dr : (r == 1) ? sr : (r == 2) ? dc : sc;
  const int* src = (r == 0) ? sr : (r == 1) ? dr : (r == 2) ? sc : dc;
  int d = dst[e];
  int pos = rowptr[r*(N_NODES+1) + d] + atomicAdd(&cur[r*N_NODES + d], 1);
  colsrc[r*N_EDGES + pos] = src[e];
}

// ---------------- per-relation GAT aggregation: writes relu(conv) fp32 to d_out ----------------
// one wave per (node, relation); lane owns 4 cols (single head k0 = lane>>3)
__global__ __launch_bounds__(256) void aggregate_k(
    const int* __restrict__ rowptr, const int* __restrict__ colsrc,
    const float* __restrict__ EL, const float* __restrict__ ER,
    const u16* __restrict__ P, float* __restrict__ NR){
  const int r = blockIdx.y;
  const int wave = threadIdx.x >> 6, lane = threadIdx.x & 63;
  const int n = blockIdx.x*4 + wave;
  if (n >= N_NODES) return;
  const int k0 = lane >> 3;
  const int rp0 = rowptr[r*(N_NODES+1) + n], rp1 = rowptr[r*(N_NODES+1) + n + 1];
  const float er = ER[(size_t)r*NE8 + n*8 + k0];
  const float* el = EL + (size_t)r*NE8;
  const int* cs = colsrc + r*N_EDGES;
  const u16* Ps = P + (size_t)(r ^ 1)*NP;

  float m = -1e30f;
  for (int e = rp0; e < rp1; ++e){
    int s = cs[e];
    m = fmaxf(m, leaky(el[s*8 + k0] + er));
  }
  float z = 0.f, a0 = 0.f, a1 = 0.f, a2 = 0.f, a3 = 0.f;
  for (int e = rp0; e < rp1; ++e){
    int s = cs[e];
    float ex = __expf(leaky(el[s*8 + k0] + er) - m);
    z += ex;
    ushort4 h = *(const ushort4*)(Ps + (size_t)s*256 + lane*4);
    a0 += ex * bf2f(h.x); a1 += ex * bf2f(h.y); a2 += ex * bf2f(h.z); a3 += ex * bf2f(h.w);
  }
  float inv = (rp1 > rp0) ? 1.f / z : 0.f;
  f32x4 o;
  o[0] = fmaxf(a0*inv, 0.f);
  o[1] = fmaxf(a1*inv, 0.f);
  o[2] = fmaxf(a2*inv, 0.f);
  o[3] = fmaxf(a3*inv, 0.f);
  *(f32x4*)(NR + (size_t)r*NP + (size_t)n*256 + lane*4) = o;
}

// ---------------- cross-relation attention (groups {0,2} and {1,3}), fp32 in-place on d_out ----------------
__global__ __launch_bounds__(256) void cross_k(const float* __restrict__ rel_attn,
                                               float* __restrict__ out){
  const int g = blockIdx.y;                    // group: relations {g, g+2}
  const int wave = threadIdx.x >> 6, lane = threadIdx.x & 63;
  const int n = blockIdx.x*4 + wave;
  if (n >= N_NODES) return;
  const int k0 = lane >> 3;
  f32x4 h0 = *(const f32x4*)(out + (size_t)g*NP       + (size_t)n*256 + lane*4);
  f32x4 h1 = *(const f32x4*)(out + (size_t)(g + 2)*NP + (size_t)n*256 + lane*4);
#pragma unroll
  for (int which = 0; which < 2; ++which){
    int rr = g + which*2;
    const float* ra = rel_attn + rr*256 + k0*32 + (lane & 7)*4;
    float s0 = 0.f, s1 = 0.f;
#pragma unroll
    for (int j = 0; j < 4; ++j){
      float a = ra[j];
      s0 += a * h0[j]; s1 += a * h1[j];
    }
    s0 += __shfl_xor(s0, 1); s1 += __shfl_xor(s1, 1);
    s0 += __shfl_xor(s0, 2); s1 += __shfl_xor(s1, 2);
    s0 += __shfl_xor(s0, 4); s1 += __shfl_xor(s1, 4);
    float l0 = leaky(s0), l1 = leaky(s1);
    float mx = fmaxf(l0, l1);
    float e0 = __expf(l0 - mx), e1 = __expf(l1 - mx);
    float w0 = e0 / (e0 + e1), w1 = 1.f - w0;
    f32x4 o;
#pragma unroll
    for (int j = 0; j < 4; ++j) o[j] = w0*h0[j] + w1*h1[j];
    *(f32x4*)(out + ((size_t)rr*N_NODES + n)*256 + lane*4) = o;
  }
}

extern "C" void kernel_launch(void* const* d_in, const int* in_sizes, int n_in,
                              void* d_out, int out_size, void* d_ws, size_t ws_size,
                              hipStream_t stream) {
  (void)in_sizes; (void)n_in; (void)out_size; (void)ws_size;
  const float* feats      = (const float*)d_in[0];
  const float* rel_feats  = (const float*)d_in[1];
  const int*   src_rates  = (const int*)d_in[2];
  const int*   dst_rates  = (const int*)d_in[3];
  const int*   src_clicks = (const int*)d_in[4];
  const int*   dst_clicks = (const int*)d_in[5];
  const float* W_node     = (const float*)d_in[6];
  const float* Wr         = (const float*)d_in[7];
  const float* Wres       = (const float*)d_in[8];
  const float* bres       = (const float*)d_in[9];
  const float* resw       = (const float*)d_in[10];
  const float* rel_attn   = (const float*)d_in[11];
  const float* Wupd       = (const float*)d_in[12];
  const float* bupd       = (const float*)d_in[13];

  char* w = (char*)d_ws;
  u16*   Wp     = (u16*)(w + WP_OFF);
  float* attn   = (float*)(w + ATTN_OFF);
  float* alpha  = (float*)(w + ALPHA_OFF);
  u16*   P      = (u16*)(w + P_OFF);
  float* EL     = (float*)(w + EL_OFF);
  float* ER     = (float*)(w + ER_OFF);
  int*   counts = (int*)(w + CNT_OFF);
  int*   cur    = (int*)(w + CUR_OFF);
  int*   rowptr = (int*)(w + ROW_OFF);
  int*   bsums  = (int*)(w + BS_OFF);
  int*   colsrc = (int*)(w + COL_OFF);
  float* out    = (float*)d_out;

  static const int DT[4] = {1, 0, 1, 0};   // DTYPE per relation / feat index

  // zero counts + cursors (contiguous: 400000 ints)
  zero_k<<<1563, 256, 0, stream>>>(counts, 400000);
  small_k<<<4, 256, 0, stream>>>(rel_feats, Wr, Wupd, bupd, resw, attn, alpha,
                                 out + (size_t)4*NP);
  prepack_k<<<1024, 256, 0, stream>>>(W_node, Wres, Wp);

  hist_k<<<dim3(1172, 4), 256, 0, stream>>>(src_rates, dst_rates, src_clicks, dst_clicks, counts);
  scan1_k<<<dim3(196, 4), 256, 0, stream>>>(counts, rowptr, bsums);
  scan2_k<<<1, 256, 0, stream>>>(bsums);
  scan3_k<<<dim3(196, 4), 256, 0, stream>>>(bsums, rowptr);
  scatter_k<<<dim3(1172, 4), 256, 0, stream>>>(src_rates, dst_rates, src_clicks, dst_clicks,
                                               rowptr, cur, colsrc);

  // projections P[i] = bf16(feats[i] @ W_node[DT[i]])
  for (int i = 0; i < 4; ++i)
    gemm_k<<<782, 256, 0, stream>>>(feats + (size_t)i*NP, Wp + DT[i]*65536, nullptr,
                                    alpha, 0, P + (size_t)i*NP, nullptr);

  elr_k<<<dim3(1563, 4), 256, 0, stream>>>(P, attn, EL, ER);
  // conv (pre-residual, relu'd) -> d_out fp32
  aggregate_k<<<dim3(12500, 4), 256, 0, stream>>>(rowptr, colsrc, EL, ER, P, out);
  // residual blend in-place: out = al*conv + (1-al)*(feats@Wres + bres)
  for (int r = 0; r < 4; ++r)
    gemm_k<<<782, 256, 0, stream>>>(feats + (size_t)r*NP, Wp + (2 + DT[r])*65536,
                                    bres + DT[r]*256, alpha, DT[r],
                                    nullptr, out + (size_t)r*NP);

  cross_k<<<dim3(12500, 2), 256, 0, stream>>>(rel_attn, out);
}